// Round 1
// 584.423 us; speedup vs baseline: 1.0047x; 1.0047x over previous
//
#include <hip/hip_runtime.h>

typedef unsigned short u16b;
typedef __attribute__((ext_vector_type(8))) short short8;
typedef __attribute__((ext_vector_type(4))) float float4v;

#define DEV __device__ __forceinline__

DEV float b2f(u16b u){ union{unsigned int i; float f;} x; x.i=((unsigned int)u)<<16; return x.f; }
DEV u16b f2b(float f){ union{float f; unsigned int i;} x; x.f=f;
  return (u16b)((x.i + 0x7fffu + ((x.i>>16)&1u))>>16); }

// async global->LDS DMA, 16B per lane; lds must be the wave-uniform base.
DEV void g2l16(const u16b* g, u16b* l){
  __builtin_amdgcn_global_load_lds(
      (const __attribute__((address_space(1))) void*)g,
      (__attribute__((address_space(3))) void*)l, 16, 0, 0);
}

// Load 8 consecutive elements as bf16, converting from f32 if flag==0.
DEV short8 ld8(const void* base, size_t idx, int f){
  if (f) return *(const short8*)((const u16b*)base + idx);
  const float* p = (const float*)base + idx;
  float4v a = *(const float4v*)p;
  float4v b = *(const float4v*)(p+4);
  short8 r;
  r[0]=(short)f2b(a[0]); r[1]=(short)f2b(a[1]); r[2]=(short)f2b(a[2]); r[3]=(short)f2b(a[3]);
  r[4]=(short)f2b(b[0]); r[5]=(short)f2b(b[1]); r[6]=(short)f2b(b[2]); r[7]=(short)f2b(b[3]);
  return r;
}

// ---------------------------------------------------------------------------
// Dtype sniffer: bf16 (flag=1) vs f32 (flag=0).
// ---------------------------------------------------------------------------
__global__ void sniff_k(const void* __restrict__ qk, int* __restrict__ flag){
  const u16b* u = (const u16b*)qk;
  int t = threadIdx.x;
  u16b x = u[(size_t)2*t*257];
  int e = (x>>7)&0xFF;
  int ok = (e>=100 && e<=134 && (x&0x7FFF)!=0) ? 1 : 0;
  unsigned long long b = __ballot(ok);
  __shared__ int cnt[4];
  if ((t&63)==0) cnt[t>>6] = __popcll(b);
  __syncthreads();
  if (t==0) *flag = (cnt[0]+cnt[1]+cnt[2]+cnt[3] >= 128) ? 1 : 0;
}

// ---------------------------------------------------------------------------
// Ingest: convert 9 small tensors (weights/biases/masks) to canonical bf16.
// ---------------------------------------------------------------------------
struct IngestArgs {
  const void* src[9];
  int n[9];
  int off[9];
};

__global__ __launch_bounds__(256)
void ingest_k(IngestArgs a, u16b* __restrict__ dst, const int* __restrict__ flag){
  const int f = *flag;
  const int stride = gridDim.x*blockDim.x;
#pragma unroll
  for (int t=0;t<9;t++){
    const void* s = a.src[t];
    int n = a.n[t], o = a.off[t];
    for (int i = blockIdx.x*blockDim.x + threadIdx.x; i < n; i += stride){
      float v = f ? b2f(((const u16b*)s)[i]) : ((const float*)s)[i];
      dst[o + i] = f2b(v);
    }
  }
}

// ---------------------------------------------------------------------------
// Transpose+convert both inputs. R1: 4 column-tiles (64r x 256c) per block,
// loads for all 4 tiles batched in one basic block (dtype branch hoisted) so
// 8-16 global loads are in flight per thread before any convert/pack; one
// barrier per 4 tiles; 4096 blocks instead of 16384.
// Per tile: u32-pair pack into LDS u32[32][65] (stride 65 -> <=2 lanes/bank,
// free). Read phase gathers 4 u32 = out[c][8r..8r+7] as one 16B store.
//  z<8 : qk [1024][4096] batch z   -> Xtq [4096][1024] bf16
//  z>=8: v  [1024][4096] batch z-8 -> Xtv [4096][1024] bf16
// ---------------------------------------------------------------------------
__global__ __launch_bounds__(256,4)
void transpose2_k(const void* __restrict__ qk, const void* __restrict__ vv,
                  u16b* __restrict__ outq, u16b* __restrict__ outv,
                  const int* __restrict__ flag)
{
  __shared__ unsigned int X[4][2080];        // 4 x u32[32][65], 33280 B
  const int f = *flag;
  const int R = 1024, C = 4096;
  const int z = blockIdx.z;
  const void* in = (z<8) ? qk : vv;
  u16b* out = (z<8) ? outq : outv;
  const int zz = z&7;
  const int c0 = blockIdx.x*256;
  const int r0 = blockIdx.y*64;
  const size_t base = (size_t)zz * (size_t)R * (size_t)C;
  const int t = threadIdx.x;
  const int r2 = t>>3, c8 = t&7;
  const size_t ra = base + (size_t)(r0 + 2*r2    )*C + c0 + c8*8;
  const size_t rb = base + (size_t)(r0 + 2*r2 + 1)*C + c0 + c8*8;

  if (f){
    // bf16 input: 8 x 16B loads, all issued before packing
    const u16b* p = (const u16b*)in;
    short8 va[4], vb[4];
#pragma unroll
    for (int tt=0;tt<4;tt++) va[tt] = *(const short8*)(p + ra + tt*64);
#pragma unroll
    for (int tt=0;tt<4;tt++) vb[tt] = *(const short8*)(p + rb + tt*64);
#pragma unroll
    for (int tt=0;tt<4;tt++)
#pragma unroll
      for (int k=0;k<8;k++){
        unsigned int w = (((unsigned int)(unsigned short)vb[tt][k])<<16)
                       |  (unsigned int)(unsigned short)va[tt][k];
        X[tt][r2*65 + c8*8 + k] = w;
      }
  } else {
    // f32 input: 16 x 16B loads, all issued before any convert
    const float* p = (const float*)in;
    float4v a[4][2], b[4][2];
#pragma unroll
    for (int tt=0;tt<4;tt++){
      a[tt][0] = *(const float4v*)(p + ra + tt*64);
      a[tt][1] = *(const float4v*)(p + ra + tt*64 + 4);
    }
#pragma unroll
    for (int tt=0;tt<4;tt++){
      b[tt][0] = *(const float4v*)(p + rb + tt*64);
      b[tt][1] = *(const float4v*)(p + rb + tt*64 + 4);
    }
#pragma unroll
    for (int tt=0;tt<4;tt++)
#pragma unroll
      for (int k=0;k<8;k++){
        float fa = a[tt][k>>2][k&3];
        float fb = b[tt][k>>2][k&3];
        unsigned int w = (((unsigned int)f2b(fb))<<16)
                       |  (unsigned int)f2b(fa);
        X[tt][r2*65 + c8*8 + k] = w;
      }
  }
  __syncthreads();
#pragma unroll
  for (int tt=0;tt<4;tt++)
#pragma unroll
    for (int i=0;i<2;i++){
      int idx = i*256 + t;
      int c = idx>>3, rq = idx&7;
      unsigned int d0 = X[tt][(4*rq+0)*65 + c];
      unsigned int d1 = X[tt][(4*rq+1)*65 + c];
      unsigned int d2 = X[tt][(4*rq+2)*65 + c];
      unsigned int d3 = X[tt][(4*rq+3)*65 + c];
      uint4 o; o.x=d0; o.y=d1; o.z=d2; o.w=d3;
      *(uint4*)&out[base + (size_t)(c0 + tt*64 + c)*R + r0 + 8*rq] = o;
    }
}

// ---------------------------------------------------------------------------
// GEMM: C[m][n] = sum_k A[m*K+k]*B[n*K+k]  (both k-major bf16), m97-style:
// global_load_lds dwordx4 staging into XOR-swizzled unpadded LDS.
// MODE 1: += bias[m], store C[m*N+n]                   (V proj, C=[e][bs])
// MODE 2: += bias[m], *= mask[n], remap out[b][m][s], f32-or-bf16 by flag
// MODE 3: += bias[n]; n<512 -> QT[m][n], else KT[m][n-512] (KT = QT+16M elems)
// ---------------------------------------------------------------------------
template<int MODE>
__global__ __launch_bounds__(256,2)
void gemm_kt(const u16b* __restrict__ A, const u16b* __restrict__ B,
             void* __restrict__ Cv, const u16b* __restrict__ bias,
             const u16b* __restrict__ mask, const int* __restrict__ flag,
             int M, int N, int K)
{
  __shared__ __align__(16) u16b a_sh[4096];   // 128 rows x 32 k, swizzled, 8KB
  __shared__ __align__(16) u16b b_sh[4096];
  const int f = (MODE==2) ? *flag : 0;
  const int tid  = threadIdx.x;
  const int lane = tid & 63;
  const int wv   = tid >> 6;
  const int wm   = (wv>>1)*64, wn = (wv&1)*64;
  const int q    = lane>>4, ln = lane&15;
  const int m0   = blockIdx.y*128, n0 = blockIdx.x*128;

  const int L0 = wv*64 + lane;
  const int r0s = L0>>2;
  const int kc0 = (L0&3) ^ ((r0s>>1)&3);
  const int L1 = (wv+4)*64 + lane;
  const int r1s = L1>>2;
  const int kc1 = (L1&3) ^ ((r1s>>1)&3);
  const size_t ga0 = (size_t)(m0+r0s)*K + (kc0<<3);
  const size_t ga1 = (size_t)(m0+r1s)*K + (kc1<<3);
  const size_t gb0 = (size_t)(n0+r0s)*K + (kc0<<3);
  const size_t gb1 = (size_t)(n0+r1s)*K + (kc1<<3);

  const int sw  = (q ^ ((ln>>1)&3))<<3;
  const int aoff = (wm+ln)*32 + sw;
  const int boff = (wn+ln)*32 + sw;

  float4v acc[4][4];
#pragma unroll
  for (int i=0;i<4;i++)
#pragma unroll
    for (int j=0;j<4;j++) acc[i][j] = float4v{0.f,0.f,0.f,0.f};

  for (int k0=0; k0<K; k0+=32){
    __syncthreads();
    g2l16(&A[ga0 + k0], &a_sh[wv*512]);
    g2l16(&A[ga1 + k0], &a_sh[(wv+4)*512]);
    g2l16(&B[gb0 + k0], &b_sh[wv*512]);
    g2l16(&B[gb1 + k0], &b_sh[(wv+4)*512]);
    asm volatile("s_waitcnt vmcnt(0)" ::: "memory");
    __syncthreads();
    short8 af[4], bfr[4];
#pragma unroll
    for (int mt=0;mt<4;mt++) af[mt]  = *(const short8*)&a_sh[aoff + mt*512];
#pragma unroll
    for (int nt=0;nt<4;nt++) bfr[nt] = *(const short8*)&b_sh[boff + nt*512];
#pragma unroll
    for (int mt=0;mt<4;mt++)
#pragma unroll
      for (int nt=0;nt<4;nt++)
        acc[mt][nt] = __builtin_amdgcn_mfma_f32_16x16x32_bf16(
            af[mt], bfr[nt], acc[mt][nt], 0,0,0);
  }

#pragma unroll
  for (int mt=0;mt<4;mt++)
#pragma unroll
    for (int nt=0;nt<4;nt++)
#pragma unroll
      for (int r=0;r<4;r++){
        int gm = m0 + wm + mt*16 + q*4 + r;
        int gn = n0 + wn + nt*16 + ln;
        float v = acc[mt][nt][r];
        if (MODE==3) v += b2f(bias[gn]);
        else         v += b2f(bias[gm]);
        if (MODE==2){
          v *= b2f(mask[gn]);
          size_t oidx = ((size_t)(gn>>12)*1024 + gm)*4096 + (gn&4095);
          if (f) ((u16b*)Cv)[oidx] = f2b(v);
          else   ((float*)Cv)[oidx] = v;
        } else if (MODE==3){
          u16b* dst = (u16b*)Cv + ((size_t)(gn>>9)<<24);  // +16M elems if K-half
          dst[(size_t)gm*512 + (gn&511)] = f2b(v);
        } else {
          ((u16b*)Cv)[(size_t)gm*N + gn] = f2b(v);
        }
      }
}

// ---------------------------------------------------------------------------
// Windowed attention per (window w, head h). 4 waves, 32 q-rows each.
// QT/KT: [32768][512] (s-major). V2: [512][32768] (e-major). GT aliases KT
// (block-private tile; all K reads precede the barrier, GT writes follow).
// ---------------------------------------------------------------------------
__global__ __launch_bounds__(256,2)
void attn_k(const u16b* __restrict__ QT, const u16b* __restrict__ KT,
            const u16b* __restrict__ V2, const u16b* __restrict__ mask,
            u16b* __restrict__ GT)
{
  __shared__ u16b v_sh[64][136];
  __shared__ u16b p_sh[4][32][136];
  const int bid = blockIdx.x;
  const int w = bid>>3, h = bid&7;
  const int tid = threadIdx.x, lane = tid&63, wv = tid>>6;
  const int q = lane>>4, ln = lane&15;
  const size_t cb = (size_t)w*128;

#pragma unroll
  for (int i=0;i<4;i++){
    int idx=i*256+tid, row=idx>>4, ch=(idx&15)*8;
    *(short8*)&v_sh[row][ch] =
        *(const short8*)&V2[(size_t)(h*64+row)*32768 + cb + ch];
  }

  short8 qf[2][2], kf[8][2];
#pragma unroll
  for (int mt=0;mt<2;mt++)
#pragma unroll
    for (int ks=0;ks<2;ks++)
      qf[mt][ks] = *(const short8*)&QT[(cb + wv*32 + mt*16 + ln)*512 + h*64 + ks*32 + q*8];
#pragma unroll
  for (int nt=0;nt<8;nt++)
#pragma unroll
    for (int ks=0;ks<2;ks++)
      kf[nt][ks] = *(const short8*)&KT[(cb + nt*16 + ln)*512 + h*64 + ks*32 + q*8];

  float4v sa[2][8];
#pragma unroll
  for (int mt=0;mt<2;mt++)
#pragma unroll
    for (int nt=0;nt<8;nt++) sa[mt][nt] = float4v{0.f,0.f,0.f,0.f};
#pragma unroll
  for (int ks=0;ks<2;ks++)
#pragma unroll
    for (int mt=0;mt<2;mt++)
#pragma unroll
      for (int nt=0;nt<8;nt++)
        sa[mt][nt] = __builtin_amdgcn_mfma_f32_16x16x32_bf16(
            qf[mt][ks], kf[nt][ks], sa[mt][nt], 0,0,0);

  float mk[8];
#pragma unroll
  for (int nt=0;nt<8;nt++) mk[nt] = b2f(mask[cb + nt*16 + ln]);
#pragma unroll
  for (int mt=0;mt<2;mt++)
#pragma unroll
    for (int nt=0;nt<8;nt++)
#pragma unroll
      for (int r=0;r<4;r++){
        float s = sa[mt][nt][r]*0.125f;          // /sqrt(dh=64)
        sa[mt][nt][r] = (mk[nt] > 0.0f) ? s : -1e9f;
      }

  float mrow[2][4], lrow[2][4];
#pragma unroll
  for (int mt=0;mt<2;mt++)
#pragma unroll
    for (int r=0;r<4;r++){
      float m = -3e38f;
#pragma unroll
      for (int nt=0;nt<8;nt++) m = fmaxf(m, sa[mt][nt][r]);
#pragma unroll
      for (int d=1; d<16; d<<=1) m = fmaxf(m, __shfl_xor(m, d));
      mrow[mt][r] = m;
    }
#pragma unroll
  for (int mt=0;mt<2;mt++)
#pragma unroll
    for (int nt=0;nt<8;nt++)
#pragma unroll
      for (int r=0;r<4;r++)
        sa[mt][nt][r] = __expf(sa[mt][nt][r] - mrow[mt][r]);
#pragma unroll
  for (int mt=0;mt<2;mt++)
#pragma unroll
    for (int r=0;r<4;r++){
      float l = 0.f;
#pragma unroll
      for (int nt=0;nt<8;nt++) l += sa[mt][nt][r];
#pragma unroll
      for (int d=1; d<16; d<<=1) l += __shfl_xor(l, d);
      lrow[mt][r] = l;
    }

#pragma unroll
  for (int mt=0;mt<2;mt++)
#pragma unroll
    for (int nt=0;nt<8;nt++)
#pragma unroll
      for (int r=0;r<4;r++)
        p_sh[wv][mt*16 + q*4 + r][nt*16 + ln] = f2b(sa[mt][nt][r]);
  __syncthreads();   // covers v_sh staging, p_sh, and all KT(GT-alias) reads

  float4v oa[2][4];
#pragma unroll
  for (int mt=0;mt<2;mt++)
#pragma unroll
    for (int nt=0;nt<4;nt++) oa[mt][nt] = float4v{0.f,0.f,0.f,0.f};
#pragma unroll
  for (int ks=0;ks<4;ks++){
    short8 pf[2], vf[4];
#pragma unroll
    for (int mt=0;mt<2;mt++) pf[mt] = *(const short8*)&p_sh[wv][mt*16+ln][ks*32+q*8];
#pragma unroll
    for (int nt=0;nt<4;nt++) vf[nt] = *(const short8*)&v_sh[nt*16+ln][ks*32+q*8];
#pragma unroll
    for (int mt=0;mt<2;mt++)
#pragma unroll
      for (int nt=0;nt<4;nt++)
        oa[mt][nt] = __builtin_amdgcn_mfma_f32_16x16x32_bf16(
            pf[mt], vf[nt], oa[mt][nt], 0,0,0);
  }

#pragma unroll
  for (int mt=0;mt<2;mt++)
#pragma unroll
    for (int nt=0;nt<4;nt++)
#pragma unroll
      for (int r=0;r<4;r++){
        float x = oa[mt][nt][r] * (1.0f / lrow[mt][r]);
        float g = 0.5f * x * (1.0f + erff(x * 0.70710678118f));
        GT[(cb + wv*32 + mt*16 + q*4 + r)*512 + h*64 + nt*16 + ln] = f2b(g);
      }
}

// ---------------------------------------------------------------------------
extern "C" void kernel_launch(void* const* d_in, const int* in_sizes, int n_in,
                              void* d_out, int out_size, void* d_ws, size_t ws_size,
                              hipStream_t stream)
{
  const void* qk    = d_in[0];
  const void* v     = d_in[1];
  const void* masks = d_in[2];

  char* ws = (char*)d_ws;
  int*  flag  = (int*)ws;                          // [0,1KB)
  u16b* wbase = (u16b*)(ws + 1024);                // canonical bf16 weights
  const int OWQ=0, OWK=524288, OWV=1048576, OWO=1572864;
  const int OBQ=2097152, OBK=2097664, OBV=2098176, OBO=2098688, OMSK=2099712;

  u16b* QT  = (u16b*)(ws + ((size_t)  8<<20));     // [32768][512] 32MB
  u16b* KT  = (u16b*)(ws + ((size_t) 40<<20));     // [32768][512] 32MB (=QT+16M)
  u16b* V2  = (u16b*)(ws + ((size_t) 72<<20));     // [512][32768] 32MB
  u16b* Xtq = (u16b*)(ws + ((size_t)104<<20));     // [32768][1024] 64MB
  u16b* Xtv = (u16b*)(ws + ((size_t)168<<20));     // [32768][1024] 64MB
  u16b* GT  = KT;

  sniff_k<<<1,256,0,stream>>>(qk, flag);

  IngestArgs ia;
  ia.src[0]=d_in[3]; ia.n[0]=524288; ia.off[0]=OWQ;   // Wq
  ia.src[1]=d_in[5]; ia.n[1]=524288; ia.off[1]=OWK;   // Wk
  ia.src[2]=d_in[7]; ia.n[2]=524288; ia.off[2]=OWV;   // Wv
  ia.src[3]=d_in[9]; ia.n[3]=524288; ia.off[3]=OWO;   // Wo
  ia.src[4]=d_in[4]; ia.n[4]=512;    ia.off[4]=OBQ;   // bq
  ia.src[5]=d_in[6]; ia.n[5]=512;    ia.off[5]=OBK;   // bk  (adjacent to bq)
  ia.src[6]=d_in[8]; ia.n[6]=512;    ia.off[6]=OBV;   // bv
  ia.src[7]=d_in[10];ia.n[7]=1024;   ia.off[7]=OBO;   // bo
  ia.src[8]=masks;   ia.n[8]=32768;  ia.off[8]=OMSK;  // masks
  ingest_k<<<1024,256,0,stream>>>(ia, wbase, flag);

  transpose2_k<<<dim3(16,16,16),256,0,stream>>>(qk, v, Xtq, Xtv, flag);
  // fused Q+K projection: B rows = [Wq ; Wk] (contiguous in wbase)
  gemm_kt<3><<<dim3(8,256),256,0,stream>>>(Xtq, wbase+OWQ, QT, wbase+OBQ, nullptr, flag, 32768, 1024, 1024);
  gemm_kt<1><<<dim3(256,4),256,0,stream>>>(wbase+OWV, Xtv, V2, wbase+OBV, nullptr, flag, 512, 32768, 1024);
  attn_k<<<2048,256,0,stream>>>(QT, KT, V2, wbase+OMSK, GT);
  gemm_kt<2><<<dim3(256,8),256,0,stream>>>(wbase+OWO, GT, d_out, wbase+OBO, wbase+OMSK, flag, 1024, 32768, 512);
}

// Round 2
// 579.042 us; speedup vs baseline: 1.0140x; 1.0093x over previous
//
#include <hip/hip_runtime.h>

typedef unsigned short u16b;
typedef __attribute__((ext_vector_type(8))) short short8;
typedef __attribute__((ext_vector_type(4))) float float4v;

#define DEV __device__ __forceinline__

DEV float b2f(u16b u){ union{unsigned int i; float f;} x; x.i=((unsigned int)u)<<16; return x.f; }
DEV u16b f2b(float f){ union{float f; unsigned int i;} x; x.f=f;
  return (u16b)((x.i + 0x7fffu + ((x.i>>16)&1u))>>16); }

// async global->LDS DMA, 16B per lane; lds must be the wave-uniform base.
DEV void g2l16(const u16b* g, u16b* l){
  __builtin_amdgcn_global_load_lds(
      (const __attribute__((address_space(1))) void*)g,
      (__attribute__((address_space(3))) void*)l, 16, 0, 0);
}

// Load 8 consecutive elements as bf16, converting from f32 if flag==0.
DEV short8 ld8(const void* base, size_t idx, int f){
  if (f) return *(const short8*)((const u16b*)base + idx);
  const float* p = (const float*)base + idx;
  float4v a = *(const float4v*)p;
  float4v b = *(const float4v*)(p+4);
  short8 r;
  r[0]=(short)f2b(a[0]); r[1]=(short)f2b(a[1]); r[2]=(short)f2b(a[2]); r[3]=(short)f2b(a[3]);
  r[4]=(short)f2b(b[0]); r[5]=(short)f2b(b[1]); r[6]=(short)f2b(b[2]); r[7]=(short)f2b(b[3]);
  return r;
}

// ---------------------------------------------------------------------------
// Dtype sniffer: bf16 (flag=1) vs f32 (flag=0).
// ---------------------------------------------------------------------------
__global__ void sniff_k(const void* __restrict__ qk, int* __restrict__ flag){
  const u16b* u = (const u16b*)qk;
  int t = threadIdx.x;
  u16b x = u[(size_t)2*t*257];
  int e = (x>>7)&0xFF;
  int ok = (e>=100 && e<=134 && (x&0x7FFF)!=0) ? 1 : 0;
  unsigned long long b = __ballot(ok);
  __shared__ int cnt[4];
  if ((t&63)==0) cnt[t>>6] = __popcll(b);
  __syncthreads();
  if (t==0) *flag = (cnt[0]+cnt[1]+cnt[2]+cnt[3] >= 128) ? 1 : 0;
}

// ---------------------------------------------------------------------------
// Ingest: convert 9 small tensors (weights/biases/masks) to canonical bf16.
// ---------------------------------------------------------------------------
struct IngestArgs {
  const void* src[9];
  int n[9];
  int off[9];
};

__global__ __launch_bounds__(256)
void ingest_k(IngestArgs a, u16b* __restrict__ dst, const int* __restrict__ flag){
  const int f = *flag;
  const int stride = gridDim.x*blockDim.x;
#pragma unroll
  for (int t=0;t<9;t++){
    const void* s = a.src[t];
    int n = a.n[t], o = a.off[t];
    for (int i = blockIdx.x*blockDim.x + threadIdx.x; i < n; i += stride){
      float v = f ? b2f(((const u16b*)s)[i]) : ((const float*)s)[i];
      dst[o + i] = f2b(v);
    }
  }
}

// ---------------------------------------------------------------------------
// Transpose+convert ONE tensor (v only now; qk handled by fused proj_qk_k).
// 4 column-tiles (64r x 256c) per block; u32-pair LDS scheme, conflict-free.
//  v [1024][4096] batch z -> Xtv [4096][1024] bf16
// ---------------------------------------------------------------------------
__global__ __launch_bounds__(256,4)
void transpose1_k(const void* __restrict__ in, u16b* __restrict__ out,
                  const int* __restrict__ flag)
{
  __shared__ unsigned int X[4][2080];        // 4 x u32[32][65]
  const int f = *flag;
  const int C = 4096;
  const int zz = blockIdx.z;
  const int c0 = blockIdx.x*256;
  const int r0 = blockIdx.y*64;
  const size_t base = (size_t)zz * (size_t)1024 * (size_t)C;
  const int t = threadIdx.x;
  const int r2 = t>>3, c8 = t&7;
  const size_t ra = base + (size_t)(r0 + 2*r2    )*C + c0 + c8*8;
  const size_t rb = base + (size_t)(r0 + 2*r2 + 1)*C + c0 + c8*8;

  if (f){
    const u16b* p = (const u16b*)in;
    short8 va[4], vb[4];
#pragma unroll
    for (int tt=0;tt<4;tt++) va[tt] = *(const short8*)(p + ra + tt*64);
#pragma unroll
    for (int tt=0;tt<4;tt++) vb[tt] = *(const short8*)(p + rb + tt*64);
#pragma unroll
    for (int tt=0;tt<4;tt++)
#pragma unroll
      for (int k=0;k<8;k++){
        unsigned int w = (((unsigned int)(unsigned short)vb[tt][k])<<16)
                       |  (unsigned int)(unsigned short)va[tt][k];
        X[tt][r2*65 + c8*8 + k] = w;
      }
  } else {
    const float* p = (const float*)in;
    float4v a[4][2], b[4][2];
#pragma unroll
    for (int tt=0;tt<4;tt++){
      a[tt][0] = *(const float4v*)(p + ra + tt*64);
      a[tt][1] = *(const float4v*)(p + ra + tt*64 + 4);
    }
#pragma unroll
    for (int tt=0;tt<4;tt++){
      b[tt][0] = *(const float4v*)(p + rb + tt*64);
      b[tt][1] = *(const float4v*)(p + rb + tt*64 + 4);
    }
#pragma unroll
    for (int tt=0;tt<4;tt++)
#pragma unroll
      for (int k=0;k<8;k++){
        float fa = a[tt][k>>2][k&3];
        float fb = b[tt][k>>2][k&3];
        unsigned int w = (((unsigned int)f2b(fb))<<16)
                       |  (unsigned int)f2b(fa);
        X[tt][r2*65 + c8*8 + k] = w;
      }
  }
  __syncthreads();
#pragma unroll
  for (int tt=0;tt<4;tt++)
#pragma unroll
    for (int i=0;i<2;i++){
      int idx = i*256 + t;
      int c = idx>>3, rq = idx&7;
      unsigned int d0 = X[tt][(4*rq+0)*65 + c];
      unsigned int d1 = X[tt][(4*rq+1)*65 + c];
      unsigned int d2 = X[tt][(4*rq+2)*65 + c];
      unsigned int d3 = X[tt][(4*rq+3)*65 + c];
      uint4 o; o.x=d0; o.y=d1; o.z=d2; o.w=d3;
      *(uint4*)&out[base + (size_t)(c0 + tt*64 + c)*1024 + r0 + 8*rq] = o;
    }
}

// ---------------------------------------------------------------------------
// Fused transpose + Q/K projection. Reads qk [b][d][s] (f32 or bf16)
// directly; per k-step (BK=64) transposes two 64d x 64s sub-tiles via the
// u32-pair LDS scheme into XOR-swizzled a_sh[128s][64k]; Wqk staged via
// global_load_lds with pre-swizzled source (linear dest, rule 21).
// Grid 2048 flat: p = (flat>>6)*8 + (flat&7) (m-panel), nt = (flat>>3)&7.
// The 8 blocks sharing an A-panel are flat = const (mod 8) within a
// 64-window -> same XCD, temporally adjacent -> A re-reads hit that XCD L2.
// Epilogue == old MODE3: +bias[gn]; gn<512 -> QT, else KT (=QT+16M elems).
// ---------------------------------------------------------------------------
DEV void loadA_f32(const float* __restrict__ src, int k0, int r2, int c8, int s0,
                   float4v (&F)[8]){
#pragma unroll
  for (int st=0;st<2;st++)
#pragma unroll
    for (int j=0;j<2;j++)
#pragma unroll
      for (int h=0;h<2;h++)
        F[st*4+j*2+h] = *(const float4v*)&src[(size_t)(k0+2*r2+j)*4096
                                              + s0 + st*64 + c8*8 + h*4];
}

DEV void loadA_bf16(const u16b* __restrict__ src, int k0, int r2, int c8, int s0,
                    short8 (&H)[4]){
#pragma unroll
  for (int st=0;st<2;st++)
#pragma unroll
    for (int j=0;j<2;j++)
      H[st*2+j] = *(const short8*)&src[(size_t)(k0+2*r2+j)*4096
                                       + s0 + st*64 + c8*8];
}

template<bool BF>
DEV void proj_step(const void* __restrict__ qkv, size_t bbase,
                   const u16b* __restrict__ Wqk,
                   int k0, int kn, int n0, int s0,
                   int t, int lane, int wv, int q, int ln, int r2, int c8,
                   int wm, int wn,
                   float4v (&Fc)[8], short8 (&Hc)[4],
                   float4v (&Fn)[8], short8 (&Hn)[4],
                   unsigned int (*X)[2088],
                   u16b* __restrict__ a_sh, u16b* __restrict__ b_sh,
                   float4v (&acc)[4][4])
{
  __syncthreads();                                   // B1: prev reads done
  // prefetch next A k-slice (issued before g2l16 so vmcnt(0) covers all)
  if (BF) loadA_bf16((const u16b*)qkv + bbase, kn, r2, c8, s0, Hn);
  else    loadA_f32 ((const float*)qkv + bbase, kn, r2, c8, s0, Fn);
  // stage B (Wqk) via global_load_lds: linear dest, source k-group pre-swizzled
#pragma unroll
  for (int pp=0; pp<4; pp++){
    int r = (pp*4+wv)*8 + (lane>>3);
    int g = lane&7;
    g2l16(&Wqk[(size_t)(n0+r)*1024 + k0 + ((g ^ ((r>>1)&7))<<3)],
          &b_sh[(pp*4+wv)*512]);
  }
  // pack current A (2 sub-tiles 64d x 64s) into X as (d-even, d-odd) u32 pairs
#pragma unroll
  for (int st=0;st<2;st++)
#pragma unroll
    for (int k=0;k<8;k++){
      unsigned int w;
      if (BF) w = (((unsigned int)(unsigned short)Hc[st*2+1][k])<<16)
                |  (unsigned int)(unsigned short)Hc[st*2+0][k];
      else    w = (((unsigned int)f2b(Fc[st*4+2+(k>>2)][k&3]))<<16)
                |  (unsigned int)f2b(Fc[st*4+0+(k>>2)][k&3]);
      X[st][r2*65 + c8*8 + k] = w;
    }
  __syncthreads();                                   // B2: X visible
  // unpack: gather 8 consecutive d for one s, write swizzled a_sh row
#pragma unroll
  for (int st=0;st<2;st++)
#pragma unroll
    for (int i=0;i<2;i++){
      int idx = i*256 + t;
      int c = idx>>3, rq = idx&7;
      unsigned int d0 = X[st][(4*rq+0)*65 + c];
      unsigned int d1 = X[st][(4*rq+1)*65 + c];
      unsigned int d2 = X[st][(4*rq+2)*65 + c];
      unsigned int d3 = X[st][(4*rq+3)*65 + c];
      int s = st*64 + c;
      uint4 o; o.x=d0; o.y=d1; o.z=d2; o.w=d3;
      *(uint4*)&a_sh[s*64 + ((rq ^ ((s>>1)&7))<<3)] = o;
    }
  asm volatile("s_waitcnt vmcnt(0)" ::: "memory");   // b_sh landed (+A pref)
  __syncthreads();                                   // B3: a_sh visible
#pragma unroll
  for (int k2=0;k2<2;k2++){
    short8 af[4], bf[4];
#pragma unroll
    for (int mt=0;mt<4;mt++){
      int row = wm + mt*16 + ln;
      af[mt] = *(const short8*)&a_sh[row*64 + (((k2*4+q) ^ ((row>>1)&7))<<3)];
    }
#pragma unroll
    for (int nf=0;nf<4;nf++){
      int row = wn + nf*16 + ln;
      bf[nf] = *(const short8*)&b_sh[row*64 + (((k2*4+q) ^ ((row>>1)&7))<<3)];
    }
#pragma unroll
    for (int mt=0;mt<4;mt++)
#pragma unroll
      for (int nf=0;nf<4;nf++)
        acc[mt][nf] = __builtin_amdgcn_mfma_f32_16x16x32_bf16(
            af[mt], bf[nf], acc[mt][nf], 0,0,0);
  }
}

__global__ __launch_bounds__(256,2)
void proj_qk_k(const void* __restrict__ qkv, const u16b* __restrict__ Wqk,
               u16b* __restrict__ QT, const u16b* __restrict__ bias,
               const int* __restrict__ flag)
{
  __shared__ unsigned int X[2][2088];                // 16.7 KB
  __shared__ __align__(16) u16b a_sh[8192];          // 16 KB [128][64] swz
  __shared__ __align__(16) u16b b_sh[8192];          // 16 KB [128][64] swz

  const int flat = blockIdx.x;
  const int p  = ((flat>>6)<<3) + (flat&7);          // m-panel 0..255
  const int nt = (flat>>3)&7;                        // n-tile 0..7
  const int m0 = p*128, n0 = nt*128;
  const size_t bbase = (size_t)(m0>>12) * (size_t)(1024*4096);
  const int s0 = m0 & 4095;
  const int t = threadIdx.x, lane = t&63, wv = t>>6;
  const int q = lane>>4, ln = lane&15;
  const int r2 = t>>3, c8 = t&7;
  const int wm = (wv>>1)*64, wn = (wv&1)*64;

  float4v acc[4][4];
#pragma unroll
  for (int i=0;i<4;i++)
#pragma unroll
    for (int j=0;j<4;j++) acc[i][j] = float4v{0.f,0.f,0.f,0.f};

  float4v F0[8], F1[8]; short8 H0[4], H1[4];
  const int f = *flag;
  if (f){
    loadA_bf16((const u16b*)qkv + bbase, 0, r2, c8, s0, H0);
    for (int kk=0; kk<16; kk+=2){
      int k0 = kk*64;
      proj_step<true>(qkv, bbase, Wqk, k0,      (k0+ 64<1024)?k0+ 64:0, n0, s0,
                      t, lane, wv, q, ln, r2, c8, wm, wn,
                      F0, H0, F1, H1, X, a_sh, b_sh, acc);
      proj_step<true>(qkv, bbase, Wqk, k0+64,   (k0+128<1024)?k0+128:0, n0, s0,
                      t, lane, wv, q, ln, r2, c8, wm, wn,
                      F1, H1, F0, H0, X, a_sh, b_sh, acc);
    }
  } else {
    loadA_f32((const float*)qkv + bbase, 0, r2, c8, s0, F0);
    for (int kk=0; kk<16; kk+=2){
      int k0 = kk*64;
      proj_step<false>(qkv, bbase, Wqk, k0,      (k0+ 64<1024)?k0+ 64:0, n0, s0,
                       t, lane, wv, q, ln, r2, c8, wm, wn,
                       F0, H0, F1, H1, X, a_sh, b_sh, acc);
      proj_step<false>(qkv, bbase, Wqk, k0+64,   (k0+128<1024)?k0+128:0, n0, s0,
                       t, lane, wv, q, ln, r2, c8, wm, wn,
                       F1, H1, F0, H0, X, a_sh, b_sh, acc);
    }
  }

#pragma unroll
  for (int mt=0;mt<4;mt++)
#pragma unroll
    for (int nf=0;nf<4;nf++)
#pragma unroll
      for (int r=0;r<4;r++){
        int gm = m0 + wm + mt*16 + q*4 + r;
        int gn = n0 + wn + nf*16 + ln;
        float v = acc[mt][nf][r] + b2f(bias[gn]);
        u16b* dst = QT + ((size_t)(gn>>9)<<24);      // +16M elems if K-half
        dst[(size_t)gm*512 + (gn&511)] = f2b(v);
      }
}

// ---------------------------------------------------------------------------
// GEMM: C[m][n] = sum_k A[m*K+k]*B[n*K+k]  (both k-major bf16), m97-style:
// global_load_lds dwordx4 staging into XOR-swizzled unpadded LDS.
// MODE 1: += bias[m], store C[m*N+n]                   (V proj, C=[e][bs])
// MODE 2: += bias[m], *= mask[n], remap out[b][m][s], f32-or-bf16 by flag
// ---------------------------------------------------------------------------
template<int MODE>
__global__ __launch_bounds__(256,2)
void gemm_kt(const u16b* __restrict__ A, const u16b* __restrict__ B,
             void* __restrict__ Cv, const u16b* __restrict__ bias,
             const u16b* __restrict__ mask, const int* __restrict__ flag,
             int M, int N, int K)
{
  __shared__ __align__(16) u16b a_sh[4096];   // 128 rows x 32 k, swizzled, 8KB
  __shared__ __align__(16) u16b b_sh[4096];
  const int f = (MODE==2) ? *flag : 0;
  const int tid  = threadIdx.x;
  const int lane = tid & 63;
  const int wv   = tid >> 6;
  const int wm   = (wv>>1)*64, wn = (wv&1)*64;
  const int q    = lane>>4, ln = lane&15;
  const int m0   = blockIdx.y*128, n0 = blockIdx.x*128;

  const int L0 = wv*64 + lane;
  const int r0s = L0>>2;
  const int kc0 = (L0&3) ^ ((r0s>>1)&3);
  const int L1 = (wv+4)*64 + lane;
  const int r1s = L1>>2;
  const int kc1 = (L1&3) ^ ((r1s>>1)&3);
  const size_t ga0 = (size_t)(m0+r0s)*K + (kc0<<3);
  const size_t ga1 = (size_t)(m0+r1s)*K + (kc1<<3);
  const size_t gb0 = (size_t)(n0+r0s)*K + (kc0<<3);
  const size_t gb1 = (size_t)(n0+r1s)*K + (kc1<<3);

  const int sw  = (q ^ ((ln>>1)&3))<<3;
  const int aoff = (wm+ln)*32 + sw;
  const int boff = (wn+ln)*32 + sw;

  float4v acc[4][4];
#pragma unroll
  for (int i=0;i<4;i++)
#pragma unroll
    for (int j=0;j<4;j++) acc[i][j] = float4v{0.f,0.f,0.f,0.f};

  for (int k0=0; k0<K; k0+=32){
    __syncthreads();
    g2l16(&A[ga0 + k0], &a_sh[wv*512]);
    g2l16(&A[ga1 + k0], &a_sh[(wv+4)*512]);
    g2l16(&B[gb0 + k0], &b_sh[wv*512]);
    g2l16(&B[gb1 + k0], &b_sh[(wv+4)*512]);
    asm volatile("s_waitcnt vmcnt(0)" ::: "memory");
    __syncthreads();
    short8 af[4], bfr[4];
#pragma unroll
    for (int mt=0;mt<4;mt++) af[mt]  = *(const short8*)&a_sh[aoff + mt*512];
#pragma unroll
    for (int nt=0;nt<4;nt++) bfr[nt] = *(const short8*)&b_sh[boff + nt*512];
#pragma unroll
    for (int mt=0;mt<4;mt++)
#pragma unroll
      for (int nt=0;nt<4;nt++)
        acc[mt][nt] = __builtin_amdgcn_mfma_f32_16x16x32_bf16(
            af[mt], bfr[nt], acc[mt][nt], 0,0,0);
  }

#pragma unroll
  for (int mt=0;mt<4;mt++)
#pragma unroll
    for (int nt=0;nt<4;nt++)
#pragma unroll
      for (int r=0;r<4;r++){
        int gm = m0 + wm + mt*16 + q*4 + r;
        int gn = n0 + wn + nt*16 + ln;
        float v = acc[mt][nt][r];
        v += b2f(bias[gm]);
        if (MODE==2){
          v *= b2f(mask[gn]);
          size_t oidx = ((size_t)(gn>>12)*1024 + gm)*4096 + (gn&4095);
          if (f) ((u16b*)Cv)[oidx] = f2b(v);
          else   ((float*)Cv)[oidx] = v;
        } else {
          ((u16b*)Cv)[(size_t)gm*N + gn] = f2b(v);
        }
      }
}

// ---------------------------------------------------------------------------
// Windowed attention per (window w, head h). 4 waves, 32 q-rows each.
// QT/KT: [32768][512] (s-major). V2: [512][32768] (e-major). GT aliases KT
// (block-private tile; all K reads precede the barrier, GT writes follow).
// ---------------------------------------------------------------------------
__global__ __launch_bounds__(256,2)
void attn_k(const u16b* __restrict__ QT, const u16b* __restrict__ KT,
            const u16b* __restrict__ V2, const u16b* __restrict__ mask,
            u16b* __restrict__ GT)
{
  __shared__ u16b v_sh[64][136];
  __shared__ u16b p_sh[4][32][136];
  const int bid = blockIdx.x;
  const int w = bid>>3, h = bid&7;
  const int tid = threadIdx.x, lane = tid&63, wv = tid>>6;
  const int q = lane>>4, ln = lane&15;
  const size_t cb = (size_t)w*128;

#pragma unroll
  for (int i=0;i<4;i++){
    int idx=i*256+tid, row=idx>>4, ch=(idx&15)*8;
    *(short8*)&v_sh[row][ch] =
        *(const short8*)&V2[(size_t)(h*64+row)*32768 + cb + ch];
  }

  short8 qf[2][2], kf[8][2];
#pragma unroll
  for (int mt=0;mt<2;mt++)
#pragma unroll
    for (int ks=0;ks<2;ks++)
      qf[mt][ks] = *(const short8*)&QT[(cb + wv*32 + mt*16 + ln)*512 + h*64 + ks*32 + q*8];
#pragma unroll
  for (int nt=0;nt<8;nt++)
#pragma unroll
    for (int ks=0;ks<2;ks++)
      kf[nt][ks] = *(const short8*)&KT[(cb + nt*16 + ln)*512 + h*64 + ks*32 + q*8];

  float4v sa[2][8];
#pragma unroll
  for (int mt=0;mt<2;mt++)
#pragma unroll
    for (int nt=0;nt<8;nt++) sa[mt][nt] = float4v{0.f,0.f,0.f,0.f};
#pragma unroll
  for (int ks=0;ks<2;ks++)
#pragma unroll
    for (int mt=0;mt<2;mt++)
#pragma unroll
      for (int nt=0;nt<8;nt++)
        sa[mt][nt] = __builtin_amdgcn_mfma_f32_16x16x32_bf16(
            qf[mt][ks], kf[nt][ks], sa[mt][nt], 0,0,0);

  float mk[8];
#pragma unroll
  for (int nt=0;nt<8;nt++) mk[nt] = b2f(mask[cb + nt*16 + ln]);
#pragma unroll
  for (int mt=0;mt<2;mt++)
#pragma unroll
    for (int nt=0;nt<8;nt++)
#pragma unroll
      for (int r=0;r<4;r++){
        float s = sa[mt][nt][r]*0.125f;          // /sqrt(dh=64)
        sa[mt][nt][r] = (mk[nt] > 0.0f) ? s : -1e9f;
      }

  float mrow[2][4], lrow[2][4];
#pragma unroll
  for (int mt=0;mt<2;mt++)
#pragma unroll
    for (int r=0;r<4;r++){
      float m = -3e38f;
#pragma unroll
      for (int nt=0;nt<8;nt++) m = fmaxf(m, sa[mt][nt][r]);
#pragma unroll
      for (int d=1; d<16; d<<=1) m = fmaxf(m, __shfl_xor(m, d));
      mrow[mt][r] = m;
    }
#pragma unroll
  for (int mt=0;mt<2;mt++)
#pragma unroll
    for (int nt=0;nt<8;nt++)
#pragma unroll
      for (int r=0;r<4;r++)
        sa[mt][nt][r] = __expf(sa[mt][nt][r] - mrow[mt][r]);
#pragma unroll
  for (int mt=0;mt<2;mt++)
#pragma unroll
    for (int r=0;r<4;r++){
      float l = 0.f;
#pragma unroll
      for (int nt=0;nt<8;nt++) l += sa[mt][nt][r];
#pragma unroll
      for (int d=1; d<16; d<<=1) l += __shfl_xor(l, d);
      lrow[mt][r] = l;
    }

#pragma unroll
  for (int mt=0;mt<2;mt++)
#pragma unroll
    for (int nt=0;nt<8;nt++)
#pragma unroll
      for (int r=0;r<4;r++)
        p_sh[wv][mt*16 + q*4 + r][nt*16 + ln] = f2b(sa[mt][nt][r]);
  __syncthreads();   // covers v_sh staging, p_sh, and all KT(GT-alias) reads

  float4v oa[2][4];
#pragma unroll
  for (int mt=0;mt<2;mt++)
#pragma unroll
    for (int nt=0;nt<4;nt++) oa[mt][nt] = float4v{0.f,0.f,0.f,0.f};
#pragma unroll
  for (int ks=0;ks<4;ks++){
    short8 pf[2], vf[4];
#pragma unroll
    for (int mt=0;mt<2;mt++) pf[mt] = *(const short8*)&p_sh[wv][mt*16+ln][ks*32+q*8];
#pragma unroll
    for (int nt=0;nt<4;nt++) vf[nt] = *(const short8*)&v_sh[nt*16+ln][ks*32+q*8];
#pragma unroll
    for (int mt=0;mt<2;mt++)
#pragma unroll
      for (int nt=0;nt<4;nt++)
        oa[mt][nt] = __builtin_amdgcn_mfma_f32_16x16x32_bf16(
            pf[mt], vf[nt], oa[mt][nt], 0,0,0);
  }

#pragma unroll
  for (int mt=0;mt<2;mt++)
#pragma unroll
    for (int nt=0;nt<4;nt++)
#pragma unroll
      for (int r=0;r<4;r++){
        float x = oa[mt][nt][r] * (1.0f / lrow[mt][r]);
        float g = 0.5f * x * (1.0f + erff(x * 0.70710678118f));
        GT[(cb + wv*32 + mt*16 + q*4 + r)*512 + h*64 + nt*16 + ln] = f2b(g);
      }
}

// ---------------------------------------------------------------------------
extern "C" void kernel_launch(void* const* d_in, const int* in_sizes, int n_in,
                              void* d_out, int out_size, void* d_ws, size_t ws_size,
                              hipStream_t stream)
{
  const void* qk    = d_in[0];
  const void* v     = d_in[1];
  const void* masks = d_in[2];

  char* ws = (char*)d_ws;
  int*  flag  = (int*)ws;                          // [0,1KB)
  u16b* wbase = (u16b*)(ws + 1024);                // canonical bf16 weights
  const int OWQ=0, OWK=524288, OWV=1048576, OWO=1572864;
  const int OBQ=2097152, OBK=2097664, OBV=2098176, OBO=2098688, OMSK=2099712;

  u16b* QT  = (u16b*)(ws + ((size_t)  8<<20));     // [32768][512] 32MB
  u16b* KT  = (u16b*)(ws + ((size_t) 40<<20));     // [32768][512] 32MB (=QT+16M)
  u16b* V2  = (u16b*)(ws + ((size_t) 72<<20));     // [512][32768] 32MB
  u16b* Xtv = (u16b*)(ws + ((size_t)168<<20));     // [32768][1024] 64MB
  u16b* GT  = KT;

  sniff_k<<<1,256,0,stream>>>(qk, flag);

  IngestArgs ia;
  ia.src[0]=d_in[3]; ia.n[0]=524288; ia.off[0]=OWQ;   // Wq
  ia.src[1]=d_in[5]; ia.n[1]=524288; ia.off[1]=OWK;   // Wk
  ia.src[2]=d_in[7]; ia.n[2]=524288; ia.off[2]=OWV;   // Wv
  ia.src[3]=d_in[9]; ia.n[3]=524288; ia.off[3]=OWO;   // Wo
  ia.src[4]=d_in[4]; ia.n[4]=512;    ia.off[4]=OBQ;   // bq
  ia.src[5]=d_in[6]; ia.n[5]=512;    ia.off[5]=OBK;   // bk  (adjacent to bq)
  ia.src[6]=d_in[8]; ia.n[6]=512;    ia.off[6]=OBV;   // bv
  ia.src[7]=d_in[10];ia.n[7]=1024;   ia.off[7]=OBO;   // bo
  ia.src[8]=masks;   ia.n[8]=32768;  ia.off[8]=OMSK;  // masks
  ingest_k<<<1024,256,0,stream>>>(ia, wbase, flag);

  transpose1_k<<<dim3(16,16,8),256,0,stream>>>(v, Xtv, flag);
  // fused transpose + Q/K projection (replaces qk-transpose + MODE3 GEMM)
  proj_qk_k<<<2048,256,0,stream>>>(qk, wbase+OWQ, QT, wbase+OBQ, flag);
  gemm_kt<1><<<dim3(256,4),256,0,stream>>>(wbase+OWV, Xtv, V2, wbase+OBV, nullptr, flag, 512, 32768, 1024);
  attn_k<<<2048,256,0,stream>>>(QT, KT, V2, wbase+OMSK, GT);
  gemm_kt<2><<<dim3(256,8),256,0,stream>>>(wbase+OWO, GT, d_out, wbase+OBO, wbase+OMSK, flag, 1024, 32768, 512);
}

// Round 3
// 554.158 us; speedup vs baseline: 1.0595x; 1.0449x over previous
//
#include <hip/hip_runtime.h>

typedef unsigned short u16b;
typedef __attribute__((ext_vector_type(8))) short short8;
typedef __attribute__((ext_vector_type(4))) float float4v;

#define DEV __device__ __forceinline__

DEV float b2f(u16b u){ union{unsigned int i; float f;} x; x.i=((unsigned int)u)<<16; return x.f; }
DEV u16b f2b(float f){ union{float f; unsigned int i;} x; x.f=f;
  return (u16b)((x.i + 0x7fffu + ((x.i>>16)&1u))>>16); }

// async global->LDS DMA, 16B per lane; lds must be the wave-uniform base.
DEV void g2l16(const u16b* g, u16b* l){
  __builtin_amdgcn_global_load_lds(
      (const __attribute__((address_space(1))) void*)g,
      (__attribute__((address_space(3))) void*)l, 16, 0, 0);
}

#define LGKM0 asm volatile("s_waitcnt lgkmcnt(0)" ::: "memory")
#define SBAR  __builtin_amdgcn_s_barrier()
#define SCB0  __builtin_amdgcn_sched_barrier(0)

// ---------------------------------------------------------------------------
// Dtype sniffer: bf16 (flag=1) vs f32 (flag=0).
// ---------------------------------------------------------------------------
__global__ void sniff_k(const void* __restrict__ qk, int* __restrict__ flag){
  const u16b* u = (const u16b*)qk;
  int t = threadIdx.x;
  u16b x = u[(size_t)2*t*257];
  int e = (x>>7)&0xFF;
  int ok = (e>=100 && e<=134 && (x&0x7FFF)!=0) ? 1 : 0;
  unsigned long long b = __ballot(ok);
  __shared__ int cnt[4];
  if ((t&63)==0) cnt[t>>6] = __popcll(b);
  __syncthreads();
  if (t==0) *flag = (cnt[0]+cnt[1]+cnt[2]+cnt[3] >= 128) ? 1 : 0;
}

// ---------------------------------------------------------------------------
// Ingest: convert 9 small tensors (weights/biases/masks) to canonical bf16.
// ---------------------------------------------------------------------------
struct IngestArgs {
  const void* src[9];
  int n[9];
  int off[9];
};

__global__ __launch_bounds__(256)
void ingest_k(IngestArgs a, u16b* __restrict__ dst, const int* __restrict__ flag){
  const int f = *flag;
  const int stride = gridDim.x*blockDim.x;
#pragma unroll
  for (int t=0;t<9;t++){
    const void* s = a.src[t];
    int n = a.n[t], o = a.off[t];
    for (int i = blockIdx.x*blockDim.x + threadIdx.x; i < n; i += stride){
      float v = f ? b2f(((const u16b*)s)[i]) : ((const float*)s)[i];
      dst[o + i] = f2b(v);
    }
  }
}

// ---------------------------------------------------------------------------
// Fused transpose + projection (Q/K or V). Reads x [b][d][s] (f32 or bf16)
// directly; per k-step (BK=64) transposes two 64d x 64s sub-tiles via the
// u32-pair LDS scheme into XOR-swizzled a_sh[128s][64k]; W staged into
// DOUBLE-BUFFERED b_sh via global_load_lds one step ahead.
// K-loop uses raw s_barrier + counted s_waitcnt (never vmcnt(0)): A-prefetch
// and B-stage for step k+1 stay in flight across step k's barriers.
// OUT=0: Wqk (1024 rows), epilogue -> QT/KT split.  grid 2048.
// OUT=1: Wv (512 rows), epilogue transposes C via XF -> V2[e][s]. grid 1024.
// ---------------------------------------------------------------------------
DEV void loadA_f32(const float* __restrict__ src, int k0, int r2, int c8, int s0,
                   float4v (&F)[8]){
#pragma unroll
  for (int st=0;st<2;st++)
#pragma unroll
    for (int j=0;j<2;j++)
#pragma unroll
      for (int h=0;h<2;h++)
        F[st*4+j*2+h] = *(const float4v*)&src[(size_t)(k0+2*r2+j)*4096
                                              + s0 + st*64 + c8*8 + h*4];
}

DEV void loadA_bf16(const u16b* __restrict__ src, int k0, int r2, int c8, int s0,
                    short8 (&H)[4]){
#pragma unroll
  for (int st=0;st<2;st++)
#pragma unroll
    for (int j=0;j<2;j++)
      H[st*2+j] = *(const short8*)&src[(size_t)(k0+2*r2+j)*4096
                                       + s0 + st*64 + c8*8];
}

template<bool BF>
DEV void proj_step(const void* __restrict__ qkv, size_t bbase,
                   const u16b* __restrict__ W,
                   int k0n, int n0, int s0,
                   int t, int lane, int wv, int q, int ln, int r2, int c8,
                   int wm, int wn,
                   float4v (&Fc)[8], short8 (&Hc)[4],
                   float4v (&Fn)[8], short8 (&Hn)[4],
                   unsigned int* __restrict__ XF,
                   u16b* __restrict__ a_sh,
                   u16b* __restrict__ b_cur, u16b* __restrict__ b_nxt,
                   float4v (&acc)[4][4])
{
  // issue A(k_next) into registers (consumed by NEXT step's pack)
  if (BF) loadA_bf16((const u16b*)qkv + bbase, k0n, r2, c8, s0, Hn);
  else    loadA_f32 ((const float*)qkv + bbase, k0n, r2, c8, s0, Fn);
  // pack current A (compiler auto-waits exactly the Fc/Hc loads)
#pragma unroll
  for (int st=0;st<2;st++)
#pragma unroll
    for (int k=0;k<8;k++){
      unsigned int w;
      if (BF) w = (((unsigned int)(unsigned short)Hc[st*2+1][k])<<16)
                |  (unsigned int)(unsigned short)Hc[st*2+0][k];
      else    w = (((unsigned int)f2b(Fc[st*4+2+(k>>2)][k&3]))<<16)
                |  (unsigned int)f2b(Fc[st*4+0+(k>>2)][k&3]);
      XF[st*2176 + r2*65 + c8*8 + k] = w;
    }
  LGKM0;                 // X writes visible; frag reads of prev step retired
  SBAR;                  // B2
  SCB0;
  // stage B(k_next) into the other buffer (readers all retired pre-B2)
#pragma unroll
  for (int pp=0; pp<4; pp++){
    int r = (pp*4+wv)*8 + (lane>>3);
    int g = lane&7;
    g2l16(&W[(size_t)(n0+r)*1024 + k0n + ((g ^ ((r>>1)&7))<<3)],
          &b_nxt[(pp*4+wv)*512]);
  }
  // unpack X -> swizzled a_sh
#pragma unroll
  for (int st=0;st<2;st++)
#pragma unroll
    for (int i=0;i<2;i++){
      int idx = i*256 + t;
      int c = idx>>3, rq = idx&7;
      unsigned int d0 = XF[st*2176 + (4*rq+0)*65 + c];
      unsigned int d1 = XF[st*2176 + (4*rq+1)*65 + c];
      unsigned int d2 = XF[st*2176 + (4*rq+2)*65 + c];
      unsigned int d3 = XF[st*2176 + (4*rq+3)*65 + c];
      int s = st*64 + c;
      uint4 o; o.x=d0; o.y=d1; o.z=d2; o.w=d3;
      *(uint4*)&a_sh[s*64 + ((rq ^ ((s>>1)&7))<<3)] = o;
    }
  LGKM0;                                           // a_sh writes visible
  if (BF) asm volatile("s_waitcnt vmcnt(8)"  ::: "memory");  // drain B(k) only
  else    asm volatile("s_waitcnt vmcnt(12)" ::: "memory");  // (A+B next stay)
  SBAR;                  // B3
  SCB0;
#pragma unroll
  for (int k2=0;k2<2;k2++){
    short8 af[4], bf[4];
#pragma unroll
    for (int mt=0;mt<4;mt++){
      int row = wm + mt*16 + ln;
      af[mt] = *(const short8*)&a_sh[row*64 + (((k2*4+q) ^ ((row>>1)&7))<<3)];
    }
#pragma unroll
    for (int nf=0;nf<4;nf++){
      int row = wn + nf*16 + ln;
      bf[nf] = *(const short8*)&b_cur[row*64 + (((k2*4+q) ^ ((row>>1)&7))<<3)];
    }
#pragma unroll
    for (int mt=0;mt<4;mt++)
#pragma unroll
      for (int nf=0;nf<4;nf++)
        acc[mt][nf] = __builtin_amdgcn_mfma_f32_16x16x32_bf16(
            af[mt], bf[nf], acc[mt][nf], 0,0,0);
  }
}

template<int OUT>
__global__ __launch_bounds__(256,2)
void proj_k(const void* __restrict__ qkv, const u16b* __restrict__ W,
            u16b* __restrict__ OutP, const u16b* __restrict__ bias,
            const int* __restrict__ flag)
{
  __shared__ unsigned int XF[4352];                  // 17.4 KB
  __shared__ __align__(16) u16b a_sh[8192];          // 16 KB [128][64] swz
  __shared__ __align__(16) u16b b_sh[2][8192];       // 32 KB double-buffered

  const int flat = blockIdx.x;
  int p, nt;
  if (OUT==0){ p = ((flat>>6)<<3) + (flat&7); nt = (flat>>3)&7; }
  else       { p = ((flat>>5)<<3) + (flat&7); nt = (flat>>3)&3; }
  const int m0 = p*128, n0 = nt*128;
  const size_t bbase = (size_t)(m0>>12) * (size_t)(1024*4096);
  const int s0 = m0 & 4095;
  const int t = threadIdx.x, lane = t&63, wv = t>>6;
  const int q = lane>>4, ln = lane&15;
  const int r2 = t>>3, c8 = t&7;
  const int wm = (wv>>1)*64, wn = (wv&1)*64;

  float4v acc[4][4];
#pragma unroll
  for (int i=0;i<4;i++)
#pragma unroll
    for (int j=0;j<4;j++) acc[i][j] = float4v{0.f,0.f,0.f,0.f};

  float4v F0[8], F1[8]; short8 H0[4], H1[4];
  const int f = *flag;

  // prologue: A(0) into regs, B(0) into b_sh[0]
  if (f) loadA_bf16((const u16b*)qkv + bbase, 0, r2, c8, s0, H0);
  else   loadA_f32 ((const float*)qkv + bbase, 0, r2, c8, s0, F0);
#pragma unroll
  for (int pp=0; pp<4; pp++){
    int r = (pp*4+wv)*8 + (lane>>3);
    int g = lane&7;
    g2l16(&W[(size_t)(n0+r)*1024 + ((g ^ ((r>>1)&7))<<3)],
          &b_sh[0][(pp*4+wv)*512]);
  }

  if (f){
    for (int kk=0; kk<16; kk+=2){
      int k0 = kk*64;
      proj_step<true>(qkv, bbase, W, k0+64,          n0, s0,
                      t, lane, wv, q, ln, r2, c8, wm, wn,
                      F0, H0, F1, H1, XF, a_sh, b_sh[0], b_sh[1], acc);
      proj_step<true>(qkv, bbase, W, (k0+128)&1023,  n0, s0,
                      t, lane, wv, q, ln, r2, c8, wm, wn,
                      F1, H1, F0, H0, XF, a_sh, b_sh[1], b_sh[0], acc);
    }
  } else {
    for (int kk=0; kk<16; kk+=2){
      int k0 = kk*64;
      proj_step<false>(qkv, bbase, W, k0+64,         n0, s0,
                       t, lane, wv, q, ln, r2, c8, wm, wn,
                       F0, H0, F1, H1, XF, a_sh, b_sh[0], b_sh[1], acc);
      proj_step<false>(qkv, bbase, W, (k0+128)&1023, n0, s0,
                       t, lane, wv, q, ln, r2, c8, wm, wn,
                       F1, H1, F0, H0, XF, a_sh, b_sh[1], b_sh[0], acc);
    }
  }

  if (OUT==0){
    // QT/KT epilogue (32B-coalesced per quarter-wave)
#pragma unroll
    for (int mt=0;mt<4;mt++)
#pragma unroll
      for (int nf=0;nf<4;nf++)
#pragma unroll
        for (int r=0;r<4;r++){
          int gm = m0 + wm + mt*16 + q*4 + r;
          int gn = n0 + wn + nf*16 + ln;
          float v = acc[mt][nf][r] + b2f(bias[gn]);
          u16b* dst = OutP + ((size_t)(gn>>9)<<24);  // +16M elems if K-half
          dst[(size_t)gm*512 + (gn&511)] = f2b(v);
        }
  } else {
    // V2[e][s] epilogue: transpose C through XF (2 passes of 64 e-rows)
#pragma unroll
    for (int pass=0; pass<2; pass++){
      __syncthreads();
      if ((wv&1)==pass){
#pragma unroll
        for (int mt=0;mt<4;mt++)
#pragma unroll
          for (int nf=0;nf<4;nf++){
            int sp = (wm>>1) + mt*8 + q*2;
            int e_local = nf*16 + ln;
            float bv = b2f(bias[n0 + pass*64 + e_local]);
            float v0 = acc[mt][nf][0] + bv;
            float v1 = acc[mt][nf][1] + bv;
            float v2 = acc[mt][nf][2] + bv;
            float v3 = acc[mt][nf][3] + bv;
            XF[(sp+0)*67 + e_local] =
                (((unsigned int)f2b(v1))<<16) | (unsigned int)f2b(v0);
            XF[(sp+1)*67 + e_local] =
                (((unsigned int)f2b(v3))<<16) | (unsigned int)f2b(v2);
          }
      }
      __syncthreads();
#pragma unroll
      for (int j=0;j<4;j++){
        int e_local = j*16 + (t>>4);
        int s8 = t&15;
        unsigned int d0 = XF[(s8*4+0)*67 + e_local];
        unsigned int d1 = XF[(s8*4+1)*67 + e_local];
        unsigned int d2 = XF[(s8*4+2)*67 + e_local];
        unsigned int d3 = XF[(s8*4+3)*67 + e_local];
        uint4 o; o.x=d0; o.y=d1; o.z=d2; o.w=d3;
        *(uint4*)&OutP[(size_t)(n0 + pass*64 + e_local)*32768 + m0 + s8*8] = o;
      }
    }
  }
}

// ---------------------------------------------------------------------------
// GEMM: C[m][n] = sum_k A[m*K+k]*B[n*K+k]  (both k-major bf16), m97-style.
// MODE 2: += bias[m], *= mask[n], remap out[b][m][s], f32-or-bf16 by flag
// ---------------------------------------------------------------------------
template<int MODE>
__global__ __launch_bounds__(256,2)
void gemm_kt(const u16b* __restrict__ A, const u16b* __restrict__ B,
             void* __restrict__ Cv, const u16b* __restrict__ bias,
             const u16b* __restrict__ mask, const int* __restrict__ flag,
             int M, int N, int K)
{
  __shared__ __align__(16) u16b a_sh[4096];   // 128 rows x 32 k, swizzled, 8KB
  __shared__ __align__(16) u16b b_sh[4096];
  const int f = (MODE==2) ? *flag : 0;
  const int tid  = threadIdx.x;
  const int lane = tid & 63;
  const int wv   = tid >> 6;
  const int wm   = (wv>>1)*64, wn = (wv&1)*64;
  const int q    = lane>>4, ln = lane&15;
  const int m0   = blockIdx.y*128, n0 = blockIdx.x*128;

  const int L0 = wv*64 + lane;
  const int r0s = L0>>2;
  const int kc0 = (L0&3) ^ ((r0s>>1)&3);
  const int L1 = (wv+4)*64 + lane;
  const int r1s = L1>>2;
  const int kc1 = (L1&3) ^ ((r1s>>1)&3);
  const size_t ga0 = (size_t)(m0+r0s)*K + (kc0<<3);
  const size_t ga1 = (size_t)(m0+r1s)*K + (kc1<<3);
  const size_t gb0 = (size_t)(n0+r0s)*K + (kc0<<3);
  const size_t gb1 = (size_t)(n0+r1s)*K + (kc1<<3);

  const int sw  = (q ^ ((ln>>1)&3))<<3;
  const int aoff = (wm+ln)*32 + sw;
  const int boff = (wn+ln)*32 + sw;

  float4v acc[4][4];
#pragma unroll
  for (int i=0;i<4;i++)
#pragma unroll
    for (int j=0;j<4;j++) acc[i][j] = float4v{0.f,0.f,0.f,0.f};

  for (int k0=0; k0<K; k0+=32){
    __syncthreads();
    g2l16(&A[ga0 + k0], &a_sh[wv*512]);
    g2l16(&A[ga1 + k0], &a_sh[(wv+4)*512]);
    g2l16(&B[gb0 + k0], &b_sh[wv*512]);
    g2l16(&B[gb1 + k0], &b_sh[(wv+4)*512]);
    asm volatile("s_waitcnt vmcnt(0)" ::: "memory");
    __syncthreads();
    short8 af[4], bfr[4];
#pragma unroll
    for (int mt=0;mt<4;mt++) af[mt]  = *(const short8*)&a_sh[aoff + mt*512];
#pragma unroll
    for (int nt=0;nt<4;nt++) bfr[nt] = *(const short8*)&b_sh[boff + nt*512];
#pragma unroll
    for (int mt=0;mt<4;mt++)
#pragma unroll
      for (int nt=0;nt<4;nt++)
        acc[mt][nt] = __builtin_amdgcn_mfma_f32_16x16x32_bf16(
            af[mt], bfr[nt], acc[mt][nt], 0,0,0);
  }

#pragma unroll
  for (int mt=0;mt<4;mt++)
#pragma unroll
    for (int nt=0;nt<4;nt++)
#pragma unroll
      for (int r=0;r<4;r++){
        int gm = m0 + wm + mt*16 + q*4 + r;
        int gn = n0 + wn + nt*16 + ln;
        float v = acc[mt][nt][r];
        v += b2f(bias[gm]);
        if (MODE==2){
          v *= b2f(mask[gn]);
          size_t oidx = ((size_t)(gn>>12)*1024 + gm)*4096 + (gn&4095);
          if (f) ((u16b*)Cv)[oidx] = f2b(v);
          else   ((float*)Cv)[oidx] = v;
        } else {
          ((u16b*)Cv)[(size_t)gm*N + gn] = f2b(v);
        }
      }
}

// ---------------------------------------------------------------------------
// Windowed attention per (window w, head h). 4 waves, 32 q-rows each.
// QT/KT: [32768][512] (s-major). V2: [512][32768] (e-major). GT aliases KT
// (block-private tile; all K reads precede the barrier, GT writes follow).
// ---------------------------------------------------------------------------
__global__ __launch_bounds__(256,2)
void attn_k(const u16b* __restrict__ QT, const u16b* __restrict__ KT,
            const u16b* __restrict__ V2, const u16b* __restrict__ mask,
            u16b* __restrict__ GT)
{
  __shared__ u16b v_sh[64][136];
  __shared__ u16b p_sh[4][32][136];
  const int bid = blockIdx.x;
  const int w = bid>>3, h = bid&7;
  const int tid = threadIdx.x, lane = tid&63, wv = tid>>6;
  const int q = lane>>4, ln = lane&15;
  const size_t cb = (size_t)w*128;

#pragma unroll
  for (int i=0;i<4;i++){
    int idx=i*256+tid, row=idx>>4, ch=(idx&15)*8;
    *(short8*)&v_sh[row][ch] =
        *(const short8*)&V2[(size_t)(h*64+row)*32768 + cb + ch];
  }

  short8 qf[2][2], kf[8][2];
#pragma unroll
  for (int mt=0;mt<2;mt++)
#pragma unroll
    for (int ks=0;ks<2;ks++)
      qf[mt][ks] = *(const short8*)&QT[(cb + wv*32 + mt*16 + ln)*512 + h*64 + ks*32 + q*8];
#pragma unroll
  for (int nt=0;nt<8;nt++)
#pragma unroll
    for (int ks=0;ks<2;ks++)
      kf[nt][ks] = *(const short8*)&KT[(cb + nt*16 + ln)*512 + h*64 + ks*32 + q*8];

  float4v sa[2][8];
#pragma unroll
  for (int mt=0;mt<2;mt++)
#pragma unroll
    for (int nt=0;nt<8;nt++) sa[mt][nt] = float4v{0.f,0.f,0.f,0.f};
#pragma unroll
  for (int ks=0;ks<2;ks++)
#pragma unroll
    for (int mt=0;mt<2;mt++)
#pragma unroll
      for (int nt=0;nt<8;nt++)
        sa[mt][nt] = __builtin_amdgcn_mfma_f32_16x16x32_bf16(
            qf[mt][ks], kf[nt][ks], sa[mt][nt], 0,0,0);

  float mk[8];
#pragma unroll
  for (int nt=0;nt<8;nt++) mk[nt] = b2f(mask[cb + nt*16 + ln]);
#pragma unroll
  for (int mt=0;mt<2;mt++)
#pragma unroll
    for (int nt=0;nt<8;nt++)
#pragma unroll
      for (int r=0;r<4;r++){
        float s = sa[mt][nt][r]*0.125f;          // /sqrt(dh=64)
        sa[mt][nt][r] = (mk[nt] > 0.0f) ? s : -1e9f;
      }

  float mrow[2][4], lrow[2][4];
#pragma unroll
  for (int mt=0;mt<2;mt++)
#pragma unroll
    for (int r=0;r<4;r++){
      float m = -3e38f;
#pragma unroll
      for (int nt=0;nt<8;nt++) m = fmaxf(m, sa[mt][nt][r]);
#pragma unroll
      for (int d=1; d<16; d<<=1) m = fmaxf(m, __shfl_xor(m, d));
      mrow[mt][r] = m;
    }
#pragma unroll
  for (int mt=0;mt<2;mt++)
#pragma unroll
    for (int nt=0;nt<8;nt++)
#pragma unroll
      for (int r=0;r<4;r++)
        sa[mt][nt][r] = __expf(sa[mt][nt][r] - mrow[mt][r]);
#pragma unroll
  for (int mt=0;mt<2;mt++)
#pragma unroll
    for (int r=0;r<4;r++){
      float l = 0.f;
#pragma unroll
      for (int nt=0;nt<8;nt++) l += sa[mt][nt][r];
#pragma unroll
      for (int d=1; d<16; d<<=1) l += __shfl_xor(l, d);
      lrow[mt][r] = l;
    }

#pragma unroll
  for (int mt=0;mt<2;mt++)
#pragma unroll
    for (int nt=0;nt<8;nt++)
#pragma unroll
      for (int r=0;r<4;r++)
        p_sh[wv][mt*16 + q*4 + r][nt*16 + ln] = f2b(sa[mt][nt][r]);
  __syncthreads();   // covers v_sh staging, p_sh, and all KT(GT-alias) reads

  float4v oa[2][4];
#pragma unroll
  for (int mt=0;mt<2;mt++)
#pragma unroll
    for (int nt=0;nt<4;nt++) oa[mt][nt] = float4v{0.f,0.f,0.f,0.f};
#pragma unroll
  for (int ks=0;ks<4;ks++){
    short8 pf[2], vf[4];
#pragma unroll
    for (int mt=0;mt<2;mt++) pf[mt] = *(const short8*)&p_sh[wv][mt*16+ln][ks*32+q*8];
#pragma unroll
    for (int nt=0;nt<4;nt++) vf[nt] = *(const short8*)&v_sh[nt*16+ln][ks*32+q*8];
#pragma unroll
    for (int mt=0;mt<2;mt++)
#pragma unroll
      for (int nt=0;nt<4;nt++)
        oa[mt][nt] = __builtin_amdgcn_mfma_f32_16x16x32_bf16(
            pf[mt], vf[nt], oa[mt][nt], 0,0,0);
  }

#pragma unroll
  for (int mt=0;mt<2;mt++)
#pragma unroll
    for (int nt=0;nt<4;nt++)
#pragma unroll
      for (int r=0;r<4;r++){
        float x = oa[mt][nt][r] * (1.0f / lrow[mt][r]);
        float g = 0.5f * x * (1.0f + erff(x * 0.70710678118f));
        GT[(cb + wv*32 + mt*16 + q*4 + r)*512 + h*64 + nt*16 + ln] = f2b(g);
      }
}

// ---------------------------------------------------------------------------
extern "C" void kernel_launch(void* const* d_in, const int* in_sizes, int n_in,
                              void* d_out, int out_size, void* d_ws, size_t ws_size,
                              hipStream_t stream)
{
  const void* qk    = d_in[0];
  const void* v     = d_in[1];
  const void* masks = d_in[2];

  char* ws = (char*)d_ws;
  int*  flag  = (int*)ws;                          // [0,1KB)
  u16b* wbase = (u16b*)(ws + 1024);                // canonical bf16 weights
  const int OWQ=0, OWK=524288, OWV=1048576, OWO=1572864;
  const int OBQ=2097152, OBK=2097664, OBV=2098176, OBO=2098688, OMSK=2099712;

  u16b* QT  = (u16b*)(ws + ((size_t)  8<<20));     // [32768][512] 32MB
  u16b* KT  = (u16b*)(ws + ((size_t) 40<<20));     // [32768][512] 32MB (=QT+16M)
  u16b* V2  = (u16b*)(ws + ((size_t) 72<<20));     // [512][32768] 32MB
  u16b* GT  = KT;

  sniff_k<<<1,256,0,stream>>>(qk, flag);

  IngestArgs ia;
  ia.src[0]=d_in[3]; ia.n[0]=524288; ia.off[0]=OWQ;   // Wq
  ia.src[1]=d_in[5]; ia.n[1]=524288; ia.off[1]=OWK;   // Wk
  ia.src[2]=d_in[7]; ia.n[2]=524288; ia.off[2]=OWV;   // Wv
  ia.src[3]=d_in[9]; ia.n[3]=524288; ia.off[3]=OWO;   // Wo
  ia.src[4]=d_in[4]; ia.n[4]=512;    ia.off[4]=OBQ;   // bq
  ia.src[5]=d_in[6]; ia.n[5]=512;    ia.off[5]=OBK;   // bk  (adjacent to bq)
  ia.src[6]=d_in[8]; ia.n[6]=512;    ia.off[6]=OBV;   // bv
  ia.src[7]=d_in[10];ia.n[7]=1024;   ia.off[7]=OBO;   // bo
  ia.src[8]=masks;   ia.n[8]=32768;  ia.off[8]=OMSK;  // masks
  ingest_k<<<1024,256,0,stream>>>(ia, wbase, flag);

  // fused transpose + projections (replace transpose kernels + 2 GEMMs)
  proj_k<0><<<2048,256,0,stream>>>(qk, wbase+OWQ, QT, wbase+OBQ, flag);
  proj_k<1><<<1024,256,0,stream>>>(v,  wbase+OWV, V2, wbase+OBV, flag);
  attn_k<<<2048,256,0,stream>>>(QT, KT, V2, wbase+OMSK, GT);
  gemm_kt<2><<<dim3(256,8),256,0,stream>>>(wbase+OWO, GT, d_out, wbase+OBO, wbase+OMSK, flag, 1024, 32768, 512);
}